// Round 1
// 6125.197 us; speedup vs baseline: 1.5925x; 1.5925x over previous
//
#include <hip/hip_runtime.h>
#include <stdint.h>
#include <stddef.h>

// Problem constants (ESN_58317065945127)
#define B_    128
#define T_    2048
#define D_    128
#define H_    1024
#define O_    32
#define LAST_ 20

// Partition: 8 batch-blocks x 16 col-blocks = 128 WGs of 256 threads.
#define NB_   8
#define NC_   16
#define RING_ 4

typedef __bf16 bf16x8 __attribute__((ext_vector_type(8)));
typedef __bf16 bf16x4 __attribute__((ext_vector_type(4)));
typedef float  f32x4  __attribute__((ext_vector_type(4)));

union Pack8  { unsigned long long u;    bf16x4 v; };
union Pack16 { unsigned long long u[2]; bf16x8 v; };

__device__ __forceinline__ float tanh_fast(float s) {
    float a = fminf(fmaxf(s, -12.0f), 12.0f);
    float e = __expf(2.0f * a);
    return (e - 1.0f) / (e + 1.0f);
}

// R6: SELF-VALIDATING EXCHANGE — the flag protocol (store h -> vmcnt(0) LLC
// ack -> flag store -> consumer flag-poll -> consumer h fetch = ~4 serial LLC
// hops/step) is replaced by a lap tag embedded in the payload itself.
//
// Every published 8B word (4 bf16 of h) carries tag(t) = ((t>>2)&1)^1 in
// mantissa bit 0 of its first bf16 (<=1 ULP perturbation on 1/4 of the
// already-bf16-rounded exchange values). Each 8B word self-validates, so no
// fences/acks/flags are needed: producer fires its store and continues;
// consumers poll-load the data directly until all 16 tags match. Chain drops
// to ~2 LLC hops/step.
//
// Safety: full-h gating bounds wave drift to <=1 step, so slot (t-1)&3 is
// never overwritten while readable; successive occupants of a ring slot
// differ by 4 steps => 1 lap bit disambiguates. Tag is XOR'd with 1 so the
// 0xAA poison (bit0 = 0) reads as stale for t=0 (tag 1); we memset the ring
// to 0xAA ourselves to not depend on harness poison.
__global__ __launch_bounds__(256, 1) void esn_persist(
    const float* __restrict__ x, const float* __restrict__ w_in,
    const float* __restrict__ w_r, __bf16* __restrict__ h_ex,
    float* __restrict__ hs)
{
    __shared__ bf16x8 ls[2][16][128];   // 2 bufs x 16 batch-rows x 128 16B chunks = 64 KiB

    const int wg  = (int)blockIdx.x;
    const int bb  = wg & (NB_ - 1);  // cohort id; &7 co-lands cohort on one XCD (perf only)
    const int cb  = wg >> 3;
    const int tid = (int)threadIdx.x;
    const int wv  = tid >> 6;
    const int ln  = tid & 63;
    const int nn  = ln & 15;   // batch index within tile
    const int q   = ln >> 4;   // quad
    const int b0  = bb * 16;
    const int n0  = cb * 64 + wv * 16;

    // ---- one-time: weight fragments into registers (A-operand layout) ----
    bf16x8 win[4];                       // w_in cols, K=128 -> 4 chunks
    #pragma unroll
    for (int c = 0; c < 4; ++c) {
        bf16x8 f;
        #pragma unroll
        for (int j = 0; j < 8; ++j)
            f[j] = (__bf16)w_in[(size_t)(c * 32 + q * 8 + j) * H_ + (n0 + nn)];
        win[c] = f;
    }
    bf16x8 wr[32];                       // w_r cols, K=1024 -> 32 chunks (128 regs)
    #pragma unroll
    for (int kc = 0; kc < 32; ++kc) {
        bf16x8 f;
        #pragma unroll
        for (int j = 0; j < 8; ++j)
            f[j] = (__bf16)w_r[(size_t)(kc * 32 + q * 8 + j) * H_ + (n0 + nn)];
        wr[kc] = f;
    }

    // Spin deadline ~3s, checked every 64 poll iterations (off the fast path).
    const unsigned long long tdead =
        __builtin_amdgcn_s_memrealtime() + 300000000ull;

    const float* xrow = x + (size_t)(b0 + nn) * T_ * D_ + q * 8;  // x[b][t][k]
    const size_t hrow = (size_t)(b0 + nn) * H_;

    // x prefetch (distance 1): xn = fp32 for step t+1, xf = bf16 frags for t
    f32x4 xn[8];
    bf16x8 xf[4];
    {
        #pragma unroll
        for (int c = 0; c < 4; ++c) {
            xn[2 * c]     = *(const f32x4*)(xrow + c * 32);
            xn[2 * c + 1] = *(const f32x4*)(xrow + c * 32 + 4);
        }
        #pragma unroll
        for (int c = 0; c < 4; ++c) {
            bf16x8 f;
            #pragma unroll
            for (int j = 0; j < 4; ++j) {
                f[j]     = (__bf16)xn[2 * c][j];
                f[j + 4] = (__bf16)xn[2 * c + 1][j];
            }
            xf[c] = f;
        }
    }

    float hm0 = 0.f, hm1 = 0.f, hm2 = 0.f, hm3 = 0.f;  // fp32 master h

    for (int t = 0; t < T_; ++t) {
        // issue x loads for t+1 NOW (fly during poll + compute)
        {
            const int tn = (t + 1 < T_) ? t + 1 : T_ - 1;
            const float* xp = xrow + (size_t)tn * D_;
            #pragma unroll
            for (int c = 0; c < 4; ++c) {
                xn[2 * c]     = *(const f32x4*)(xp + c * 32);
                xn[2 * c + 1] = *(const f32x4*)(xp + c * 32 + 4);
            }
        }

        f32x4 acc0 = {0.f, 0.f, 0.f, 0.f};
        f32x4 acc1 = {0.f, 0.f, 0.f, 0.f};
        f32x4 acc2 = {0.f, 0.f, 0.f, 0.f};
        f32x4 acc3 = {0.f, 0.f, 0.f, 0.f};

        // x-projection MFMAs first: independent of the exchange, retire
        // in the matrix pipe while the poll loads are in flight.
        #pragma unroll
        for (int c = 0; c < 4; ++c)
            acc0 = __builtin_amdgcn_mfma_f32_16x16x32_bf16(win[c], xf[c], acc0, 0, 0, 0);

        if (t > 0) {
            // ---- tag-gated poll-fetch of h(t-1): the load IS the gate ----
            const unsigned long long want =
                (unsigned long long)((((t - 1) >> 2) & 1) ^ 1);
            const int sb = (t - 1) & 1;
            const __bf16* hbase = h_ex
                + (size_t)((t - 1) & (RING_ - 1)) * (B_ * H_) + (size_t)b0 * H_;
            Pack16 pk[8];
            int spins = 0;
            for (;;) {
                #pragma unroll
                for (int i = 0; i < 8; ++i) {
                    const int p = wv * 512 + i * 64 + ln;   // 16B piece index
                    const unsigned long long* gp = (const unsigned long long*)
                        (hbase + (size_t)(p >> 7) * H_ + (p & 127) * 8);
                    pk[i].u[0] = __hip_atomic_load(gp, __ATOMIC_RELAXED,
                                                   __HIP_MEMORY_SCOPE_AGENT);
                    pk[i].u[1] = __hip_atomic_load(gp + 1, __ATOMIC_RELAXED,
                                                   __HIP_MEMORY_SCOPE_AGENT);
                }
                unsigned ok = 1u;
                #pragma unroll
                for (int i = 0; i < 8; ++i) {
                    ok &= (unsigned)((pk[i].u[0] & 1ull) == want);
                    ok &= (unsigned)((pk[i].u[1] & 1ull) == want);
                }
                if (__all(ok != 0u)) break;
                __builtin_amdgcn_s_sleep(1);      // ~64 cyc backoff
                if (((++spins) & 63) == 0 &&
                    __builtin_amdgcn_s_memrealtime() > tdead) break;  // anti-hang
            }

            // ---- stage the (already loaded) quarter into LDS, XOR swizzle ----
            #pragma unroll
            for (int i = 0; i < 8; ++i) {
                const int p = wv * 512 + i * 64 + ln;
                const int r = p >> 7, ch = p & 127;
                ls[sb][r][ch ^ (r & 7)] = pk[i].v;
            }

            __syncthreads();

            // ---- recurrent MFMAs, fragments straight from LDS, 4 acc chains ----
            #pragma unroll
            for (int kc = 0; kc < 32; ++kc) {
                bf16x8 a = ls[sb][nn][(kc * 4 + q) ^ (nn & 7)];
                if      ((kc & 3) == 0) acc0 = __builtin_amdgcn_mfma_f32_16x16x32_bf16(wr[kc], a, acc0, 0, 0, 0);
                else if ((kc & 3) == 1) acc1 = __builtin_amdgcn_mfma_f32_16x16x32_bf16(wr[kc], a, acc1, 0, 0, 0);
                else if ((kc & 3) == 2) acc2 = __builtin_amdgcn_mfma_f32_16x16x32_bf16(wr[kc], a, acc2, 0, 0, 0);
                else                    acc3 = __builtin_amdgcn_mfma_f32_16x16x32_bf16(wr[kc], a, acc3, 0, 0, 0);
            }
        }

        const f32x4 acc = (acc0 + acc1) + (acc2 + acc3);
        const float th0 = tanh_fast(acc[0]);
        const float th1 = tanh_fast(acc[1]);
        const float th2 = tanh_fast(acc[2]);
        const float th3 = tanh_fast(acc[3]);
        if (t == 0) {           // reference: h = tanh(xw[:,0]), no leak at t=0
            hm0 = th0; hm1 = th1; hm2 = th2; hm3 = th3;
        } else {                // h = 0.1*h + 0.9*tanh(.)
            hm0 = 0.1f * hm0 + 0.9f * th0;
            hm1 = 0.1f * hm1 + 0.9f * th1;
            hm2 = 0.1f * hm2 + 0.9f * th2;
            hm3 = 0.1f * hm3 + 0.9f * th3;
        }

        // publish 8B packed slice with lap tag in bit 0 — fire and forget:
        // no vmcnt ack, no flag store. Consumers validate the tag per-word.
        {
            Pack8 p;
            p.v = (bf16x4){(__bf16)hm0, (__bf16)hm1, (__bf16)hm2, (__bf16)hm3};
            p.u = (p.u & ~1ull) | (unsigned long long)(((t >> 2) & 1) ^ 1);
            unsigned long long* op = (unsigned long long*)
                (h_ex + (size_t)(t & (RING_ - 1)) * (B_ * H_) + hrow + n0 + q * 4);
            __hip_atomic_store(op, p.u, __ATOMIC_RELAXED,
                               __HIP_MEMORY_SCOPE_AGENT);
        }

        // off the critical path: tail collection + x bf16 conversion for t+1
        if (t >= T_ - LAST_) {
            f32x4* sp = (f32x4*)(hs + (size_t)(t - (T_ - LAST_)) * (B_ * H_)
                                    + hrow + n0 + q * 4);
            *sp = (f32x4){hm0, hm1, hm2, hm3};
        }
        #pragma unroll
        for (int c = 0; c < 4; ++c) {
            bf16x8 f;
            #pragma unroll
            for (int j = 0; j < 4; ++j) {
                f[j]     = (__bf16)xn[2 * c][j];
                f[j + 4] = (__bf16)xn[2 * c + 1][j];
            }
            xf[c] = f;
        }
    }
}

// Readout: out[b,:] = cat(hs)[b,:] @ W + bias.  One block per batch row.
__global__ __launch_bounds__(256) void esn_out(
    const float* __restrict__ hs, const float* __restrict__ Wm,
    const float* __restrict__ bias, float* __restrict__ out)
{
    const int b   = (int)blockIdx.x;
    const int tid = (int)threadIdx.x;
    float acc[O_];
    #pragma unroll
    for (int o = 0; o < O_; ++o) acc[o] = 0.f;

    for (int k = tid; k < LAST_ * H_; k += 256) {
        // cat order: k = t'*H + c  <->  hs[t'][b][c]
        const float hv = hs[(size_t)(k >> 10) * (B_ * H_) + (size_t)b * H_ + (k & (H_ - 1))];
        const f32x4* wp = (const f32x4*)(Wm + (size_t)k * O_);
        #pragma unroll
        for (int v = 0; v < 8; ++v) {
            f32x4 w4 = wp[v];
            acc[4 * v + 0] = fmaf(hv, w4[0], acc[4 * v + 0]);
            acc[4 * v + 1] = fmaf(hv, w4[1], acc[4 * v + 1]);
            acc[4 * v + 2] = fmaf(hv, w4[2], acc[4 * v + 2]);
            acc[4 * v + 3] = fmaf(hv, w4[3], acc[4 * v + 3]);
        }
    }

    __shared__ float red[256][O_ + 1];  // +1 pad: conflict-free column sums
    #pragma unroll
    for (int o = 0; o < O_; ++o) red[tid][o] = acc[o];
    __syncthreads();
    if (tid < O_) {
        float s = bias[tid];
        for (int i = 0; i < 256; ++i) s += red[i][tid];
        out[(size_t)b * O_ + tid] = s;
    }
}

extern "C" void kernel_launch(void* const* d_in, const int* in_sizes, int n_in,
                              void* d_out, int out_size, void* d_ws, size_t ws_size,
                              hipStream_t stream)
{
    const float* x    = (const float*)d_in[0];  // [128,2048,128]
    const float* w_in = (const float*)d_in[1];  // [128,1024]
    const float* w_r  = (const float*)d_in[2];  // [1024,1024]
    const float* Wm   = (const float*)d_in[3];  // [20480,32]
    const float* bias = (const float*)d_in[4];  // [32]
    float* out        = (float*)d_out;          // [128,32]

    const size_t flag_bytes = 4096;                                      // layout compat (unused)
    const size_t hex_bytes  = (size_t)RING_ * B_ * H_ * sizeof(__bf16);  // 1 MiB
    const size_t hs_bytes   = (size_t)LAST_ * B_ * H_ * sizeof(float);   // 10 MiB
    if (ws_size < flag_bytes + hex_bytes + hs_bytes) return;  // fail loud, not corrupt

    __bf16* h_ex  = (__bf16*)((char*)d_ws + flag_bytes);
    float*  hs    = (float*)((char*)d_ws + flag_bytes + hex_bytes);

    // Self-poison the exchange ring: 0xAA => tag bit 0 = 0 = stale for t=0
    // (t=0 publishes tag 1). Do not rely on harness poison semantics.
    hipMemsetAsync(h_ex, 0xAA, hex_bytes, stream);

    hipLaunchKernelGGL(esn_persist, dim3(NB_ * NC_), dim3(256), 0, stream,
                       x, w_in, w_r, h_ex, hs);
    hipLaunchKernelGGL(esn_out, dim3(B_), dim3(256), 0, stream,
                       hs, Wm, bias, out);
}